// Round 10
// baseline (506.622 us; speedup 1.0000x reference)
//
#include <hip/hip_runtime.h>
#include <hip/hip_bf16.h>
#include <hip/hip_cooperative_groups.h>

namespace cg = cooperative_groups;

#define B_  4
#define N_  512
#define D_  128
#define H_  8
#define DK  16
#define DFF 512
#define NB  32
#define KS  8            // attention key-split
#define FS  8            // ffn2 K-split
#define GRID 512

struct Args {
    const float *h, *coords, *W_Q, *W_K, *W_V, *W_O, *emb;
    const float *w1, *b1, *w2, *b2, *g1, *be1, *g2, *be2;
    float *Qb, *Kb, *Vb, *QEb, *X1, *F1, *X2, *Pb, *Pf, *T1a, *T2a, *out;
};

#define SMEM_BYTES 34816
struct SmemQkv  { float Qls[8][132]; };
struct SmemAttn { float kl[64][16]; float vl[64][16]; float qel[64][33];
                  float ckrd[64][2]; float accl[4][64][17]; };
struct SmemOp   { float AOls[4][128]; float lsl[4][8]; };
struct SmemStat { float rs[64][4]; float rq[64][4]; float t1l[4]; float t2l[4]; };
struct SmemFfn  { float Als[16][128]; };
static_assert(sizeof(SmemAttn) <= SMEM_BYTES, "smem overflow");

__global__ __launch_bounds__(256) void mega_kernel(Args a)
{
    cg::grid_group grid = cg::this_grid();
    __shared__ __align__(16) char smem[SMEM_BYTES];

    const int bid  = blockIdx.x;
    const int tid  = threadIdx.x;
    const int wave = tid >> 6;
    const int lane = tid & 63;

    // ===== P1: QKV projections + QE (1024 virtual blocks: 256 rb x 4 z) =====
    {
        SmemQkv* sm = (SmemQkv*)smem;
        for (int vb = bid; vb < 1024; vb += GRID) {
            const int z  = vb & 3;              // 0=Q,1=K,2=V,3=QE
            const int gr0 = (vb >> 2) * 8;
            const float* Bw = (z == 1) ? a.W_K : (z == 2) ? a.W_V : a.W_Q;
            float* C = (z == 1) ? a.Kb : (z == 2) ? a.Vb : a.Qb;
            const int rbase = __builtin_amdgcn_readfirstlane(gr0 + wave * 2);
            const int col = lane * 2;

            float acc[2][2] = {};
#pragma unroll 2
            for (int k0 = 0; k0 < D_; k0 += 4) {
                float4 a0 = *(const float4*)&a.h[(size_t)(rbase + 0) * D_ + k0];
                float4 a1 = *(const float4*)&a.h[(size_t)(rbase + 1) * D_ + k0];
#pragma unroll
                for (int kk = 0; kk < 4; ++kk) {
                    float2 bv = *(const float2*)&Bw[(size_t)(k0 + kk) * D_ + col];
                    float x0 = (&a0.x)[kk], x1 = (&a1.x)[kk];
                    acc[0][0] += x0 * bv.x; acc[0][1] += x0 * bv.y;
                    acc[1][0] += x1 * bv.x; acc[1][1] += x1 * bv.y;
                }
            }
            if (z < 3) {
                *(float2*)&C[(size_t)(rbase + 0) * D_ + col] = make_float2(acc[0][0], acc[0][1]);
                *(float2*)&C[(size_t)(rbase + 1) * D_ + col] = make_float2(acc[1][0], acc[1][1]);
            } else {
                *(float2*)&sm->Qls[wave * 2 + 0][col] = make_float2(acc[0][0], acc[0][1]);
                *(float2*)&sm->Qls[wave * 2 + 1][col] = make_float2(acc[1][0], acc[1][1]);
                __syncthreads();
                const int r  = tid >> 5;
                const int hh = (tid >> 2) & 7;
                const int k0 = (tid & 3) * 8;
                const float4* qv = (const float4*)&sm->Qls[r][hh * DK];
                const float4 qa = qv[0], qb = qv[1], qc = qv[2], qd = qv[3];
                float* qe_out = a.QEb + ((size_t)(gr0 + r) * H_ + hh) * NB + k0;
#pragma unroll 2
                for (int k = 0; k < 8; ++k) {
                    const float4* ep = (const float4*)(a.emb + (size_t)(k0 + k) * D_ + hh * DK);
                    float4 e0 = ep[0], e1 = ep[1], e2 = ep[2], e3 = ep[3];
                    qe_out[k] = qa.x*e0.x + qa.y*e0.y + qa.z*e0.z + qa.w*e0.w
                              + qb.x*e1.x + qb.y*e1.y + qb.z*e1.z + qb.w*e1.w
                              + qc.x*e2.x + qc.y*e2.y + qc.z*e2.z + qc.w*e2.w
                              + qd.x*e3.x + qd.y*e3.y + qd.z*e3.z + qd.w*e3.w;
                }
                __syncthreads();
            }
        }
    }
    grid.sync();

    // ===== P2: attention partials (2048 virtual blocks, KS=8) =====
    {
        SmemAttn* sm = (SmemAttn*)smem;
        for (int vb = bid; vb < 2048; vb += GRID) {
            const int ks    = vb & 7;
            const int chunk = (vb >> 3) & 7;
            const int h     = (vb >> 6) & (H_ - 1);
            const int b     = vb >> 9;
            const int row   = b * N_ + chunk * 64 + lane;
            const size_t hdbase = (size_t)b * N_ * D_ + h * DK;

            {
                int key = tid >> 2, part = tid & 3;
                size_t g = hdbase + (size_t)(ks * 64 + key) * D_ + part * 4;
                *(float4*)&sm->kl[key][part * 4] = *(const float4*)&a.Kb[g];
                *(float4*)&sm->vl[key][part * 4] = *(const float4*)&a.Vb[g];
            }
            {
                int r = tid >> 2, part = tid & 3;
                const float* src = a.QEb + ((size_t)(b * N_ + chunk * 64 + r) * H_ + h) * NB + part * 8;
#pragma unroll
                for (int j = 0; j < 8; ++j) sm->qel[r][part * 8 + j] = src[j];
            }
            if (tid < 128)
                ((float*)sm->ckrd)[tid] = a.coords[(size_t)(b * N_ + ks * 64) * 2 + tid];

            const float4* qp = (const float4*)(a.Qb + (size_t)row * D_ + h * DK);
            const float4 q0 = qp[0], q1 = qp[1], q2 = qp[2], q3 = qp[3];
            const float cx = a.coords[(size_t)row * 2 + 0];
            const float cy = a.coords[(size_t)row * 2 + 1];

            __syncthreads();

            float l = 0.f;
            float acc[16] = {};
            const int ml0 = wave * 16;
#pragma unroll 4
            for (int i = 0; i < 16; ++i) {
                const int ml = ml0 + i;
                const float4* kp = (const float4*)&sm->kl[ml][0];
                const float4 k0 = kp[0], k1 = kp[1], k2 = kp[2], k3 = kp[3];
                float dot = q0.x*k0.x + q0.y*k0.y + q0.z*k0.z + q0.w*k0.w
                          + q1.x*k1.x + q1.y*k1.y + q1.z*k1.z + q1.w*k1.w
                          + q2.x*k2.x + q2.y*k2.y + q2.z*k2.z + q2.w*k2.w
                          + q3.x*k3.x + q3.y*k3.y + q3.z*k3.z + q3.w*k3.w;
                float dx = cx - sm->ckrd[ml][0], dy = cy - sm->ckrd[ml][1];
                float dist = sqrtf(dx * dx + dy * dy);
                int bucket = (int)(dist * 32.0f);
                bucket = bucket > (NB - 1) ? (NB - 1) : bucket;
                float s = dot * 0.25f + sm->qel[lane][bucket];
                float p = __expf(s);
                l += p;
                const float4* vp = (const float4*)&sm->vl[ml][0];
                const float4 v0 = vp[0], v1 = vp[1], v2 = vp[2], v3 = vp[3];
                acc[0]  += p * v0.x; acc[1]  += p * v0.y; acc[2]  += p * v0.z; acc[3]  += p * v0.w;
                acc[4]  += p * v1.x; acc[5]  += p * v1.y; acc[6]  += p * v1.z; acc[7]  += p * v1.w;
                acc[8]  += p * v2.x; acc[9]  += p * v2.y; acc[10] += p * v2.z; acc[11] += p * v2.w;
                acc[12] += p * v3.x; acc[13] += p * v3.y; acc[14] += p * v3.z; acc[15] += p * v3.w;
            }

            sm->accl[wave][lane][16] = l;
#pragma unroll
            for (int j = 0; j < 16; ++j) sm->accl[wave][lane][j] = acc[j];
            __syncthreads();

            float* pb = a.Pb + (size_t)vb * (64 * 17);
            for (int i = tid; i < 64 * 17; i += 256) {
                int r = i / 17, j = i - r * 17;
                pb[i] = sm->accl[0][r][j] + sm->accl[1][r][j]
                      + sm->accl[2][r][j] + sm->accl[3][r][j];
            }
            __syncthreads();
        }
    }
    grid.sync();

    // ===== P3: O-projection (4 rows/block; combine + GEMV + residual) =====
    {
        SmemOp* sm = (SmemOp*)smem;
        const int gr0 = bid * 4;

        if (tid < 32) {
            int r = tid >> 3, hh = tid & 7;
            int gr = gr0 + r;
            int b = gr >> 9, n = gr & (N_ - 1);
            int chunk = n >> 6, rl = n & 63;
            size_t base = ((size_t)(((b * H_ + hh) * 8 + chunk) * KS)) * (64 * 17) + (size_t)rl * 17;
            float l = 0.f;
#pragma unroll
            for (int s = 0; s < KS; ++s) l += a.Pb[base + (size_t)s * (64 * 17) + 16];
            sm->lsl[r][hh] = l;
        }
        float asum[2];
#pragma unroll
        for (int j = 0; j < 2; ++j) {
            int i = tid + j * 256;
            int r = i >> 7, d = i & 127;
            int gr = gr0 + r;
            int b = gr >> 9, n = gr & (N_ - 1);
            int chunk = n >> 6, rl = n & 63;
            int hh = d >> 4, dk = d & 15;
            size_t base = ((size_t)(((b * H_ + hh) * 8 + chunk) * KS)) * (64 * 17) + (size_t)rl * 17 + dk;
            float s = 0.f;
#pragma unroll
            for (int ss = 0; ss < KS; ++ss) s += a.Pb[base + (size_t)ss * (64 * 17)];
            asum[j] = s;
        }
        __syncthreads();
#pragma unroll
        for (int j = 0; j < 2; ++j) {
            int i = tid + j * 256;
            int r = i >> 7, d = i & 127;
            sm->AOls[r][d] = asum[j] / sm->lsl[r][d >> 4];
        }
        __syncthreads();

        const int col = lane * 2;
        float acc0 = 0.f, acc1 = 0.f;
#pragma unroll 2
        for (int k0 = 0; k0 < D_; k0 += 4) {
            float4 av = *(const float4*)&sm->AOls[wave][k0];
#pragma unroll
            for (int kk = 0; kk < 4; ++kk) {
                float2 bv = *(const float2*)&a.W_O[(size_t)(k0 + kk) * D_ + col];
                float x = (&av.x)[kk];
                acc0 += x * bv.x; acc1 += x * bv.y;
            }
        }
        const int gr = gr0 + wave;
        float2 rv = *(const float2*)&a.h[(size_t)gr * D_ + col];
        *(float2*)&a.X1[(size_t)gr * D_ + col] = make_float2(acc0 + rv.x, acc1 + rv.y);
    }
    grid.sync();

    // ===== P4: instance-norm-1 stats -> T1a/T2a (128 active blocks) =====
    if (bid < 128) {
        SmemStat* sm = (SmemStat*)smem;
        const int b  = bid >> 5;
        const int dg = bid & 31;
        const int dl = tid & 3;
        const int nc = tid >> 2;
        const float* xp = a.X1 + ((size_t)b * N_ + nc * 8) * D_ + dg * 4 + dl;
        float s = 0.f, q = 0.f;
#pragma unroll
        for (int i = 0; i < 8; ++i) { float x = xp[(size_t)i * D_]; s += x; q += x * x; }
        sm->rs[nc][dl] = s; sm->rq[nc][dl] = q;
        __syncthreads();
        for (int off = 32; off >= 1; off >>= 1) {
            if (nc < off) { sm->rs[nc][dl] += sm->rs[nc + off][dl];
                            sm->rq[nc][dl] += sm->rq[nc + off][dl]; }
            __syncthreads();
        }
        if (tid < 4) {
            int d = dg * 4 + tid;
            float mean = sm->rs[0][tid] * (1.0f / N_);
            float var  = sm->rq[0][tid] * (1.0f / N_) - mean * mean;
            float r = 1.0f / sqrtf(var + 1e-5f);
            float t1 = r * a.g1[d];
            a.T1a[b * D_ + d] = t1;
            a.T2a[b * D_ + d] = a.be1[d] - mean * t1;
        }
    }
    grid.sync();

    // ===== P5: FFN1 (norm prologue; relu; 16 rows x 4 slices) =====
    {
        SmemFfn* sm = (SmemFfn*)smem;
        const int gr0 = (bid >> 2) * 16;
        const int slice = bid & 3;
        const int b = gr0 >> 9;
        for (int i = tid * 4; i < 16 * 128; i += 1024) {
            int r = i >> 7, c = i & 127;
            float4 x  = *(const float4*)&a.X1[(size_t)(gr0 + r) * D_ + c];
            float4 t1 = *(const float4*)&a.T1a[b * D_ + c];
            float4 t2 = *(const float4*)&a.T2a[b * D_ + c];
            float4 y;
            y.x = x.x * t1.x + t2.x; y.y = x.y * t1.y + t2.y;
            y.z = x.z * t1.z + t2.z; y.w = x.w * t1.w + t2.w;
            *(float4*)&sm->Als[r][c] = y;
        }
        __syncthreads();

        const int rl = wave * 4;
        const int grb = __builtin_amdgcn_readfirstlane(gr0 + rl);
        const int col = slice * 128 + lane * 2;
        float acc[4][2] = {};
#pragma unroll 2
        for (int k0 = 0; k0 < D_; k0 += 4) {
            float4 a4[4];
#pragma unroll
            for (int j = 0; j < 4; ++j) a4[j] = *(const float4*)&sm->Als[rl + j][k0];
#pragma unroll
            for (int kk = 0; kk < 4; ++kk) {
                float2 bv = *(const float2*)&a.w1[(size_t)(k0 + kk) * DFF + col];
#pragma unroll
                for (int j = 0; j < 4; ++j) {
                    float x = (&a4[j].x)[kk];
                    acc[j][0] += x * bv.x; acc[j][1] += x * bv.y;
                }
            }
        }
        float2 bb = *(const float2*)&a.b1[col];
#pragma unroll
        for (int j = 0; j < 4; ++j) {
            float o0 = fmaxf(acc[j][0] + bb.x, 0.f);
            float o1 = fmaxf(acc[j][1] + bb.y, 0.f);
            *(float2*)&a.F1[(size_t)(grb + j) * DFF + col] = make_float2(o0, o1);
        }
        __syncthreads();
    }
    grid.sync();

    // ===== P6: FFN2 split-K partials (64 bx x 8 s; 8 rows/wave) =====
    {
        const int s = bid & 7, bx = bid >> 3;
        const int rbase = __builtin_amdgcn_readfirstlane((bx * 4 + wave) * 8);
        const int col = lane * 2;
        const int kbeg = s * (DFF / FS);
        float acc[8][2] = {};
#pragma unroll 2
        for (int k0 = kbeg; k0 < kbeg + DFF / FS; k0 += 4) {
            float4 a4[8];
#pragma unroll
            for (int j = 0; j < 8; ++j)
                a4[j] = *(const float4*)&a.F1[(size_t)(rbase + j) * DFF + k0];
#pragma unroll
            for (int kk = 0; kk < 4; ++kk) {
                float2 bv = *(const float2*)&a.w2[(size_t)(k0 + kk) * D_ + col];
#pragma unroll
                for (int j = 0; j < 8; ++j) {
                    float x = (&a4[j].x)[kk];
                    acc[j][0] += x * bv.x; acc[j][1] += x * bv.y;
                }
            }
        }
#pragma unroll
        for (int j = 0; j < 8; ++j)
            *(float2*)&a.Pf[((size_t)s * (B_ * N_) + rbase + j) * D_ + col] =
                make_float2(acc[j][0], acc[j][1]);
    }
    grid.sync();

    // ===== P7: FFN2 combine (+bias, + norm1(X1) residual) =====
    if (bid < 256) {
        int idx = (bid * 256 + tid) * 4;
        int d = idx & (D_ - 1);
        int b = idx >> 16;
        float4 o  = *(const float4*)&a.b2[d];
        float4 x1 = *(const float4*)&a.X1[idx];
        float4 t1 = *(const float4*)&a.T1a[b * D_ + d];
        float4 t2 = *(const float4*)&a.T2a[b * D_ + d];
        o.x += x1.x * t1.x + t2.x; o.y += x1.y * t1.y + t2.y;
        o.z += x1.z * t1.z + t2.z; o.w += x1.w * t1.w + t2.w;
#pragma unroll
        for (int s = 0; s < FS; ++s) {
            float4 p = *(const float4*)&a.Pf[(size_t)s * (B_ * N_ * D_) + idx];
            o.x += p.x; o.y += p.y; o.z += p.z; o.w += p.w;
        }
        *(float4*)&a.X2[idx] = o;
    }
    grid.sync();

    // ===== P8: instance-norm-2 stats + apply -> out (128 active) =====
    if (bid < 128) {
        SmemStat* sm = (SmemStat*)smem;
        const int b  = bid >> 5;
        const int dg = bid & 31;
        const int dl = tid & 3;
        const int nc = tid >> 2;
        const float* xp = a.X2 + ((size_t)b * N_ + nc * 8) * D_ + dg * 4 + dl;
        float s = 0.f, q = 0.f;
#pragma unroll
        for (int i = 0; i < 8; ++i) { float x = xp[(size_t)i * D_]; s += x; q += x * x; }
        sm->rs[nc][dl] = s; sm->rq[nc][dl] = q;
        __syncthreads();
        for (int off = 32; off >= 1; off >>= 1) {
            if (nc < off) { sm->rs[nc][dl] += sm->rs[nc + off][dl];
                            sm->rq[nc][dl] += sm->rq[nc + off][dl]; }
            __syncthreads();
        }
        if (tid < 4) {
            int d = dg * 4 + tid;
            float mean = sm->rs[0][tid] * (1.0f / N_);
            float var  = sm->rq[0][tid] * (1.0f / N_) - mean * mean;
            float r = 1.0f / sqrtf(var + 1e-5f);
            float t1 = r * a.g2[d];
            sm->t1l[tid] = t1;
            sm->t2l[tid] = a.be2[d] - mean * t1;
        }
        __syncthreads();
        const float t1 = sm->t1l[dl], t2 = sm->t2l[dl];
        float* yp = a.out + ((size_t)b * N_ + nc * 8) * D_ + dg * 4 + dl;
#pragma unroll
        for (int i = 0; i < 8; ++i) yp[(size_t)i * D_] = xp[(size_t)i * D_] * t1 + t2;
    }
}

// ====================== fallback kernels (verified R7 path) ======================

__global__ __launch_bounds__(256) void qkv_qe_kernel(
    const float* __restrict__ A,
    const float* __restrict__ WQ, const float* __restrict__ WK, const float* __restrict__ WV,
    const float* __restrict__ emb,
    float* __restrict__ Qo, float* __restrict__ Ko, float* __restrict__ Vo,
    float* __restrict__ QE)
{
    const float* Bw = blockIdx.z == 0 ? WQ : (blockIdx.z == 1 ? WK : WV);
    float*       C  = blockIdx.z == 0 ? Qo : (blockIdx.z == 1 ? Ko : Vo);
    const int wave = threadIdx.x >> 6;
    const int lane = threadIdx.x & 63;
    const int rbase = __builtin_amdgcn_readfirstlane((blockIdx.x * 4 + wave) * 2);
    const int col = lane * 2;

    float acc[2][2] = {};
#pragma unroll 2
    for (int k0 = 0; k0 < D_; k0 += 4) {
        float4 a0 = *(const float4*)&A[(size_t)(rbase + 0) * D_ + k0];
        float4 a1 = *(const float4*)&A[(size_t)(rbase + 1) * D_ + k0];
#pragma unroll
        for (int kk = 0; kk < 4; ++kk) {
            float2 bv = *(const float2*)&Bw[(size_t)(k0 + kk) * D_ + col];
            float x0 = (&a0.x)[kk], x1 = (&a1.x)[kk];
            acc[0][0] += x0 * bv.x; acc[0][1] += x0 * bv.y;
            acc[1][0] += x1 * bv.x; acc[1][1] += x1 * bv.y;
        }
    }
    *(float2*)&C[(size_t)(rbase + 0) * D_ + col] = make_float2(acc[0][0], acc[0][1]);
    *(float2*)&C[(size_t)(rbase + 1) * D_ + col] = make_float2(acc[1][0], acc[1][1]);

    if (blockIdx.z == 0) {
        __shared__ float Qls[8][132];
        *(float2*)&Qls[wave * 2 + 0][col] = make_float2(acc[0][0], acc[0][1]);
        *(float2*)&Qls[wave * 2 + 1][col] = make_float2(acc[1][0], acc[1][1]);
        __syncthreads();
        const int r  = threadIdx.x >> 5;
        const int hh = (threadIdx.x >> 2) & 7;
        const int k0 = (threadIdx.x & 3) * 8;
        const int grow = blockIdx.x * 8 + r;
        const float4* qv = (const float4*)&Qls[r][hh * DK];
        const float4 qa = qv[0], qb = qv[1], qc = qv[2], qd = qv[3];
        float* qe_out = QE + ((size_t)grow * H_ + hh) * NB + k0;
#pragma unroll 2
        for (int k = 0; k < 8; ++k) {
            const float4* ep = (const float4*)(emb + (size_t)(k0 + k) * D_ + hh * DK);
            float4 e0 = ep[0], e1 = ep[1], e2 = ep[2], e3 = ep[3];
            qe_out[k] = qa.x*e0.x + qa.y*e0.y + qa.z*e0.z + qa.w*e0.w
                      + qb.x*e1.x + qb.y*e1.y + qb.z*e1.z + qb.w*e1.w
                      + qc.x*e2.x + qc.y*e2.y + qc.z*e2.z + qc.w*e2.w
                      + qd.x*e3.x + qd.y*e3.y + qd.z*e3.z + qd.w*e3.w;
        }
    }
}

__global__ __launch_bounds__(256) void attn6_kernel(
    const float* __restrict__ Q, const float* __restrict__ K, const float* __restrict__ V,
    const float* __restrict__ QE, const float* __restrict__ coords,
    float* __restrict__ P)
{
    const int tid  = threadIdx.x;
    const int wave = tid >> 6;
    const int lane = tid & 63;
    const int bid  = blockIdx.x;
    const int ks    = bid & 7;
    const int chunk = (bid >> 3) & 7;
    const int h     = (bid >> 6) & (H_ - 1);
    const int b     = bid >> 9;
    const int row = b * N_ + chunk * 64 + lane;

    __shared__ float kl[64][16];
    __shared__ float vl[64][16];
    __shared__ float qel[64][NB + 1];
    __shared__ float ckrd[64][2];
    __shared__ float accl[4][64][17];

    const size_t hdbase = (size_t)b * N_ * D_ + h * DK;
    {
        int key = tid >> 2, part = tid & 3;
        size_t g = hdbase + (size_t)(ks * 64 + key) * D_ + part * 4;
        *(float4*)&kl[key][part * 4] = *(const float4*)&K[g];
        *(float4*)&vl[key][part * 4] = *(const float4*)&V[g];
    }
    {
        int r = tid >> 2, part = tid & 3;
        const float* src = QE + ((size_t)(b * N_ + chunk * 64 + r) * H_ + h) * NB + part * 8;
#pragma unroll
        for (int j = 0; j < 8; ++j) qel[r][part * 8 + j] = src[j];
    }
    if (tid < 128)
        ((float*)ckrd)[tid] = coords[(size_t)(b * N_ + ks * 64) * 2 + tid];

    const float4* qp = (const float4*)(Q + (size_t)row * D_ + h * DK);
    const float4 q0 = qp[0], q1 = qp[1], q2 = qp[2], q3 = qp[3];
    const float cx = coords[(size_t)row * 2 + 0];
    const float cy = coords[(size_t)row * 2 + 1];

    __syncthreads();

    float l = 0.f;
    float acc[16] = {};
    const int ml0 = wave * 16;
#pragma unroll 4
    for (int i = 0; i < 16; ++i) {
        const int ml = ml0 + i;
        const float4* kp = (const float4*)&kl[ml][0];
        const float4 k0 = kp[0], k1 = kp[1], k2 = kp[2], k3 = kp[3];
        float dot = q0.x*k0.x + q0.y*k0.y + q0.z*k0.z + q0.w*k0.w
                  + q1.x*k1.x + q1.y*k1.y + q1.z*k1.z + q1.w*k1.w
                  + q2.x*k2.x + q2.y*k2.y + q2.z*k2.z + q2.w*k2.w
                  + q3.x*k3.x + q3.y*k3.y + q3.z*k3.z + q3.w*k3.w;
        float dx = cx - ckrd[ml][0], dy = cy - ckrd[ml][1];
        float dist = sqrtf(dx * dx + dy * dy);
        int bucket = (int)(dist * 32.0f);
        bucket = bucket > (NB - 1) ? (NB - 1) : bucket;
        float s = dot * 0.25f + qel[lane][bucket];
        float p = __expf(s);
        l += p;
        const float4* vp = (const float4*)&vl[ml][0];
        const float4 v0 = vp[0], v1 = vp[1], v2 = vp[2], v3 = vp[3];
        acc[0]  += p * v0.x; acc[1]  += p * v0.y; acc[2]  += p * v0.z; acc[3]  += p * v0.w;
        acc[4]  += p * v1.x; acc[5]  += p * v1.y; acc[6]  += p * v1.z; acc[7]  += p * v1.w;
        acc[8]  += p * v2.x; acc[9]  += p * v2.y; acc[10] += p * v2.z; acc[11] += p * v2.w;
        acc[12] += p * v3.x; acc[13] += p * v3.y; acc[14] += p * v3.z; acc[15] += p * v3.w;
    }

    accl[wave][lane][16] = l;
#pragma unroll
    for (int j = 0; j < 16; ++j) accl[wave][lane][j] = acc[j];
    __syncthreads();

    float* pb = P + (size_t)bid * (64 * 17);
    for (int i = tid; i < 64 * 17; i += 256) {
        int r = i / 17, j = i - r * 17;
        pb[i] = accl[0][r][j] + accl[1][r][j] + accl[2][r][j] + accl[3][r][j];
    }
}

__global__ __launch_bounds__(256) void oproj_kernel(
    const float* __restrict__ P, const float* __restrict__ WO,
    const float* __restrict__ hres, float* __restrict__ X1)
{
    const int tid = threadIdx.x;
    const int gr0 = blockIdx.x * 8;
    __shared__ float AOls[8][128];
    __shared__ float lsl[8][8];

    if (tid < 64) {
        int r = tid >> 3, hh = tid & 7;
        int gr = gr0 + r;
        int b = gr >> 9, n = gr & (N_ - 1);
        int chunk = n >> 6, rl = n & 63;
        size_t base = ((size_t)(((b * H_ + hh) * 8 + chunk) * KS)) * (64 * 17) + (size_t)rl * 17;
        float l = 0.f;
#pragma unroll
        for (int s = 0; s < KS; ++s) l += P[base + (size_t)s * (64 * 17) + 16];
        lsl[r][hh] = l;
    }
    float asum[4];
#pragma unroll
    for (int j = 0; j < 4; ++j) {
        int i = tid + j * 256;
        int r = i >> 7, d = i & 127;
        int gr = gr0 + r;
        int b = gr >> 9, n = gr & (N_ - 1);
        int chunk = n >> 6, rl = n & 63;
        int hh = d >> 4, dk = d & 15;
        size_t base = ((size_t)(((b * H_ + hh) * 8 + chunk) * KS)) * (64 * 17) + (size_t)rl * 17 + dk;
        float s = 0.f;
#pragma unroll
        for (int ss = 0; ss < KS; ++ss) s += P[base + (size_t)ss * (64 * 17)];
        asum[j] = s;
    }
    __syncthreads();
#pragma unroll
    for (int j = 0; j < 4; ++j) {
        int i = tid + j * 256;
        int r = i >> 7, d = i & 127;
        AOls[r][d] = asum[j] / lsl[r][d >> 4];
    }
    __syncthreads();

    const int wave = tid >> 6;
    const int lane = tid & 63;
    const int rl = wave * 2;
    const int grb = __builtin_amdgcn_readfirstlane(gr0 + rl);
    const int col = lane * 2;

    float acc[2][2] = {};
#pragma unroll 2
    for (int k0 = 0; k0 < D_; k0 += 4) {
        float4 a0 = *(const float4*)&AOls[rl + 0][k0];
        float4 a1 = *(const float4*)&AOls[rl + 1][k0];
#pragma unroll
        for (int kk = 0; kk < 4; ++kk) {
            float2 bv = *(const float2*)&WO[(size_t)(k0 + kk) * D_ + col];
            float x0 = (&a0.x)[kk], x1 = (&a1.x)[kk];
            acc[0][0] += x0 * bv.x; acc[0][1] += x0 * bv.y;
            acc[1][0] += x1 * bv.x; acc[1][1] += x1 * bv.y;
        }
    }
#pragma unroll
    for (int j = 0; j < 2; ++j) {
        float2 rv = *(const float2*)&hres[(size_t)(grb + j) * D_ + col];
        *(float2*)&X1[(size_t)(grb + j) * D_ + col] =
            make_float2(acc[j][0] + rv.x, acc[j][1] + rv.y);
    }
}

__global__ __launch_bounds__(256) void stats_kernel(const float* __restrict__ X,
    const float* __restrict__ gamma, const float* __restrict__ beta,
    float* __restrict__ T1, float* __restrict__ T2)
{
    const int b  = blockIdx.x >> 5;
    const int dg = blockIdx.x & 31;
    const int dl = threadIdx.x & 3;
    const int nc = threadIdx.x >> 2;
    const float* xp = X + ((size_t)b * N_ + nc * 8) * D_ + dg * 4 + dl;
    float s = 0.f, q = 0.f;
#pragma unroll
    for (int i = 0; i < 8; ++i) { float x = xp[(size_t)i * D_]; s += x; q += x * x; }
    __shared__ float rs[64][4], rq[64][4];
    rs[nc][dl] = s; rq[nc][dl] = q;
    __syncthreads();
    for (int off = 32; off >= 1; off >>= 1) {
        if (nc < off) { rs[nc][dl] += rs[nc + off][dl]; rq[nc][dl] += rq[nc + off][dl]; }
        __syncthreads();
    }
    if (threadIdx.x < 4) {
        int d = dg * 4 + threadIdx.x;
        float mean = rs[0][threadIdx.x] * (1.0f / N_);
        float var  = rq[0][threadIdx.x] * (1.0f / N_) - mean * mean;
        float r = 1.0f / sqrtf(var + 1e-5f);
        float t1 = r * gamma[d];
        T1[b * D_ + d] = t1;
        T2[b * D_ + d] = beta[d] - mean * t1;
    }
}

__global__ __launch_bounds__(256) void ffn1_kernel(
    const float* __restrict__ X1, const float* __restrict__ T1, const float* __restrict__ T2,
    const float* __restrict__ w1, const float* __restrict__ b1, float* __restrict__ F1)
{
    __shared__ float Als[16][128];
    const int gr0 = blockIdx.x * 16;
    const int b = gr0 >> 9;
#pragma unroll
    for (int i = threadIdx.x * 4; i < 16 * 128; i += 1024) {
        int r = i >> 7, c = i & 127;
        float4 x  = *(const float4*)&X1[(size_t)(gr0 + r) * D_ + c];
        float4 t1 = *(const float4*)&T1[b * D_ + c];
        float4 t2 = *(const float4*)&T2[b * D_ + c];
        float4 y;
        y.x = x.x * t1.x + t2.x; y.y = x.y * t1.y + t2.y;
        y.z = x.z * t1.z + t2.z; y.w = x.w * t1.w + t2.w;
        *(float4*)&Als[r][c] = y;
    }
    __syncthreads();

    const int wave = threadIdx.x >> 6;
    const int lane = threadIdx.x & 63;
    const int rl = wave * 4;
    const int grb = __builtin_amdgcn_readfirstlane(gr0 + rl);
    const int col = blockIdx.y * 128 + lane * 2;

    float acc[4][2] = {};
#pragma unroll 2
    for (int k0 = 0; k0 < D_; k0 += 4) {
        float4 a4[4];
#pragma unroll
        for (int j = 0; j < 4; ++j) a4[j] = *(const float4*)&Als[rl + j][k0];
#pragma unroll
        for (int kk = 0; kk < 4; ++kk) {
            float2 bv = *(const float2*)&w1[(size_t)(k0 + kk) * DFF + col];
#pragma unroll
            for (int j = 0; j < 4; ++j) {
                float x = (&a4[j].x)[kk];
                acc[j][0] += x * bv.x; acc[j][1] += x * bv.y;
            }
        }
    }
    float2 bb = *(const float2*)&b1[col];
#pragma unroll
    for (int j = 0; j < 4; ++j) {
        float o0 = fmaxf(acc[j][0] + bb.x, 0.f);
        float o1 = fmaxf(acc[j][1] + bb.y, 0.f);
        *(float2*)&F1[(size_t)(grb + j) * DFF + col] = make_float2(o0, o1);
    }
}

__global__ __launch_bounds__(256) void ffn2s_kernel(
    const float* __restrict__ F1, const float* __restrict__ w2, float* __restrict__ Pf)
{
    const int wave = threadIdx.x >> 6;
    const int lane = threadIdx.x & 63;
    const int rbase = __builtin_amdgcn_readfirstlane((blockIdx.x * 4 + wave) * 4);
    const int col = lane * 2;
    const int s = blockIdx.z;
    const int kbeg = s * (DFF / FS);

    float acc[4][2] = {};
#pragma unroll 2
    for (int k0 = kbeg; k0 < kbeg + DFF / FS; k0 += 4) {
        float4 a4[4];
#pragma unroll
        for (int j = 0; j < 4; ++j)
            a4[j] = *(const float4*)&F1[(size_t)(rbase + j) * DFF + k0];
#pragma unroll
        for (int kk = 0; kk < 4; ++kk) {
            float2 bv = *(const float2*)&w2[(size_t)(k0 + kk) * D_ + col];
#pragma unroll
            for (int j = 0; j < 4; ++j) {
                float x = (&a4[j].x)[kk];
                acc[j][0] += x * bv.x; acc[j][1] += x * bv.y;
            }
        }
    }
#pragma unroll
    for (int j = 0; j < 4; ++j)
        *(float2*)&Pf[((size_t)s * (B_ * N_) + rbase + j) * D_ + col] =
            make_float2(acc[j][0], acc[j][1]);
}

__global__ __launch_bounds__(256) void fcomb_kernel(
    const float* __restrict__ Pf, const float* __restrict__ b2,
    const float* __restrict__ X1, const float* __restrict__ T1, const float* __restrict__ T2,
    float* __restrict__ X2)
{
    int idx = (blockIdx.x * 256 + threadIdx.x) * 4;
    int d = idx & (D_ - 1);
    int b = idx >> 16;
    float4 o  = *(const float4*)&b2[d];
    float4 x1 = *(const float4*)&X1[idx];
    float4 t1 = *(const float4*)&T1[b * D_ + d];
    float4 t2 = *(const float4*)&T2[b * D_ + d];
    o.x += x1.x * t1.x + t2.x; o.y += x1.y * t1.y + t2.y;
    o.z += x1.z * t1.z + t2.z; o.w += x1.w * t1.w + t2.w;
#pragma unroll
    for (int s = 0; s < FS; ++s) {
        float4 p = *(const float4*)&Pf[(size_t)s * (B_ * N_ * D_) + idx];
        o.x += p.x; o.y += p.y; o.z += p.z; o.w += p.w;
    }
    *(float4*)&X2[idx] = o;
}

__global__ __launch_bounds__(256) void stats_apply_kernel(const float* __restrict__ X,
    const float* __restrict__ gamma, const float* __restrict__ beta,
    float* __restrict__ Y)
{
    const int b  = blockIdx.x >> 5;
    const int dg = blockIdx.x & 31;
    const int dl = threadIdx.x & 3;
    const int nc = threadIdx.x >> 2;
    const float* xp = X + ((size_t)b * N_ + nc * 8) * D_ + dg * 4 + dl;
    float s = 0.f, q = 0.f;
#pragma unroll
    for (int i = 0; i < 8; ++i) { float x = xp[(size_t)i * D_]; s += x; q += x * x; }
    __shared__ float rs[64][4], rq[64][4];
    __shared__ float t1l[4], t2l[4];
    rs[nc][dl] = s; rq[nc][dl] = q;
    __syncthreads();
    for (int off = 32; off >= 1; off >>= 1) {
        if (nc < off) { rs[nc][dl] += rs[nc + off][dl]; rq[nc][dl] += rq[nc + off][dl]; }
        __syncthreads();
    }
    if (threadIdx.x < 4) {
        int d = dg * 4 + threadIdx.x;
        float mean = rs[0][threadIdx.x] * (1.0f / N_);
        float var  = rq[0][threadIdx.x] * (1.0f / N_) - mean * mean;
        float r = 1.0f / sqrtf(var + 1e-5f);
        float t1 = r * gamma[d];
        t1l[threadIdx.x] = t1;
        t2l[threadIdx.x] = beta[d] - mean * t1;
    }
    __syncthreads();
    const float t1 = t1l[dl], t2 = t2l[dl];
    float* yp = Y + ((size_t)b * N_ + nc * 8) * D_ + dg * 4 + dl;
#pragma unroll
    for (int i = 0; i < 8; ++i) yp[(size_t)i * D_] = xp[(size_t)i * D_] * t1 + t2;
}

extern "C" void kernel_launch(void* const* d_in, const int* in_sizes, int n_in,
                              void* d_out, int out_size, void* d_ws, size_t ws_size,
                              hipStream_t stream)
{
    float* ws = (float*)d_ws;
    const size_t R = (size_t)B_ * N_;

    Args a;
    a.h      = (const float*)d_in[0];
    a.coords = (const float*)d_in[1];
    a.W_Q    = (const float*)d_in[2];
    a.W_K    = (const float*)d_in[3];
    a.W_V    = (const float*)d_in[4];
    a.W_O    = (const float*)d_in[5];
    a.emb    = (const float*)d_in[6];
    a.w1     = (const float*)d_in[7];
    a.b1     = (const float*)d_in[8];
    a.w2     = (const float*)d_in[9];
    a.b2     = (const float*)d_in[10];
    a.g1     = (const float*)d_in[11];
    a.be1    = (const float*)d_in[12];
    a.g2     = (const float*)d_in[13];
    a.be2    = (const float*)d_in[14];

    a.Qb  = ws;
    a.Kb  = a.Qb + R * D_;
    a.Vb  = a.Kb + R * D_;
    a.QEb = a.Vb + R * D_;
    a.X1  = a.QEb + R * H_ * NB;
    a.F1  = a.X1 + R * D_;
    a.X2  = a.F1 + R * DFF;
    a.Pb  = a.X2 + R * D_;
    a.Pf  = a.Pb + (size_t)2048 * 64 * 17;
    a.T1a = a.Pf + (size_t)FS * R * D_;
    a.T2a = a.T1a + B_ * D_;
    a.out = (float*)d_out;

    void* params[] = { &a };
    hipError_t err = hipLaunchCooperativeKernel((const void*)mega_kernel,
                                                dim3(GRID), dim3(256), params, 0, stream);
    if (err != hipSuccess) {
        // fallback: verified 8-kernel path
        qkv_qe_kernel<<<dim3(256, 1, 3), 256, 0, stream>>>(
            a.h, a.W_Q, a.W_K, a.W_V, a.emb, a.Qb, a.Kb, a.Vb, a.QEb);
        attn6_kernel<<<dim3(2048), 256, 0, stream>>>(a.Qb, a.Kb, a.Vb, a.QEb, a.coords, a.Pb);
        oproj_kernel<<<dim3((int)R / 8), 256, 0, stream>>>(a.Pb, a.W_O, a.h, a.X1);
        stats_kernel<<<dim3(B_ * 32), 256, 0, stream>>>(a.X1, a.g1, a.be1, a.T1a, a.T2a);
        ffn1_kernel<<<dim3(128, 4), 256, 0, stream>>>(a.X1, a.T1a, a.T2a, a.w1, a.b1, a.F1);
        ffn2s_kernel<<<dim3(128, 1, FS), 256, 0, stream>>>(a.F1, a.w2, a.Pf);
        fcomb_kernel<<<dim3((int)(R * D_) / 1024), 256, 0, stream>>>(
            a.Pf, a.b2, a.X1, a.T1a, a.T2a, a.X2);
        stats_apply_kernel<<<dim3(B_ * 32), 256, 0, stream>>>(a.X2, a.g2, a.be2, a.out);
    }
}

// Round 11
// 86.204 us; speedup vs baseline: 5.8770x; 5.8770x over previous
//
#include <hip/hip_runtime.h>
#include <hip/hip_bf16.h>

#define B_  4
#define N_  512
#define D_  128
#define H_  8
#define DK  16
#define DFF 512
#define NB  32
#define KS  4            // attention key-split (keys per block = 512/KS = 128, 2 stage rounds)
#define FS  4            // ffn2 K-split

// ---------------- QKV projections + fused QE table ----------------
__global__ __launch_bounds__(256) void qkv_qe_kernel(
    const float* __restrict__ A,
    const float* __restrict__ WQ, const float* __restrict__ WK, const float* __restrict__ WV,
    const float* __restrict__ emb,
    float* __restrict__ Qo, float* __restrict__ Ko, float* __restrict__ Vo,
    float* __restrict__ QE)
{
    const float* Bw = blockIdx.z == 0 ? WQ : (blockIdx.z == 1 ? WK : WV);
    float*       C  = blockIdx.z == 0 ? Qo : (blockIdx.z == 1 ? Ko : Vo);
    const int wave = threadIdx.x >> 6;
    const int lane = threadIdx.x & 63;
    const int rbase = __builtin_amdgcn_readfirstlane((blockIdx.x * 4 + wave) * 2);
    const int col = lane * 2;

    float acc[2][2] = {};
#pragma unroll 2
    for (int k0 = 0; k0 < D_; k0 += 4) {
        float4 a0 = *(const float4*)&A[(size_t)(rbase + 0) * D_ + k0];
        float4 a1 = *(const float4*)&A[(size_t)(rbase + 1) * D_ + k0];
#pragma unroll
        for (int kk = 0; kk < 4; ++kk) {
            float2 bv = *(const float2*)&Bw[(size_t)(k0 + kk) * D_ + col];
            float x0 = (&a0.x)[kk], x1 = (&a1.x)[kk];
            acc[0][0] += x0 * bv.x; acc[0][1] += x0 * bv.y;
            acc[1][0] += x1 * bv.x; acc[1][1] += x1 * bv.y;
        }
    }
    *(float2*)&C[(size_t)(rbase + 0) * D_ + col] = make_float2(acc[0][0], acc[0][1]);
    *(float2*)&C[(size_t)(rbase + 1) * D_ + col] = make_float2(acc[1][0], acc[1][1]);

    if (blockIdx.z == 0) {
        __shared__ float Qls[8][132];
        *(float2*)&Qls[wave * 2 + 0][col] = make_float2(acc[0][0], acc[0][1]);
        *(float2*)&Qls[wave * 2 + 1][col] = make_float2(acc[1][0], acc[1][1]);
        __syncthreads();
        const int r  = threadIdx.x >> 5;
        const int hh = (threadIdx.x >> 2) & 7;
        const int k0 = (threadIdx.x & 3) * 8;
        const int grow = blockIdx.x * 8 + r;
        const float4* qv = (const float4*)&Qls[r][hh * DK];
        const float4 qa = qv[0], qb = qv[1], qc = qv[2], qd = qv[3];
        float* qe_out = QE + ((size_t)grow * H_ + hh) * NB + k0;
#pragma unroll 2
        for (int k = 0; k < 8; ++k) {
            const float4* ep = (const float4*)(emb + (size_t)(k0 + k) * D_ + hh * DK);
            float4 e0 = ep[0], e1 = ep[1], e2 = ep[2], e3 = ep[3];
            float d0 = fmaf(qa.x,e0.x, fmaf(qa.y,e0.y, fmaf(qa.z,e0.z, qa.w*e0.w)));
            float d1 = fmaf(qb.x,e1.x, fmaf(qb.y,e1.y, fmaf(qb.z,e1.z, qb.w*e1.w)));
            float d2 = fmaf(qc.x,e2.x, fmaf(qc.y,e2.y, fmaf(qc.z,e2.z, qc.w*e2.w)));
            float d3 = fmaf(qd.x,e3.x, fmaf(qd.y,e3.y, fmaf(qd.z,e3.z, qd.w*e3.w)));
            qe_out[k] = (d0 + d1) + (d2 + d3);
        }
    }
}

// ---------------- attention v7: KS=4, 2-round LDS staging, tree-dot ----------------
// grid = B*H*8*KS = 1024 blocks (34.3KB LDS -> 4/CU, exactly 1 resident batch).
// Per block: 128 keys in 2 rounds of 64; wave covers 16 keys/round.
__global__ __launch_bounds__(256) void attn7_kernel(
    const float* __restrict__ Q, const float* __restrict__ K, const float* __restrict__ V,
    const float* __restrict__ QE, const float* __restrict__ coords,
    float* __restrict__ P)
{
    const int tid  = threadIdx.x;
    const int wave = tid >> 6;
    const int lane = tid & 63;
    const int bid  = blockIdx.x;
    const int ks    = bid & 3;
    const int chunk = (bid >> 2) & 7;
    const int h     = (bid >> 5) & (H_ - 1);
    const int b     = bid >> 8;
    const int row = b * N_ + chunk * 64 + lane;

    __shared__ float kl[64][16];
    __shared__ float vl[64][16];
    __shared__ float qel[64][NB + 1];
    __shared__ float ckrd[128][2];
    __shared__ float accl[4][64][17];

    const size_t hdbase = (size_t)b * N_ * D_ + h * DK;

    {   // stage QE table (once)
        int r = tid >> 2, part = tid & 3;
        const float* src = QE + ((size_t)(b * N_ + chunk * 64 + r) * H_ + h) * NB + part * 8;
#pragma unroll
        for (int j = 0; j < 8; ++j) qel[r][part * 8 + j] = src[j];
    }
    // stage key coords for all 128 keys (once)
    ((float*)ckrd)[tid] = coords[(size_t)(b * N_ + ks * 128) * 2 + tid];

    const float4* qp = (const float4*)(Q + (size_t)row * D_ + h * DK);
    const float4 q0 = qp[0], q1 = qp[1], q2 = qp[2], q3 = qp[3];
    const float cx = coords[(size_t)row * 2 + 0];
    const float cy = coords[(size_t)row * 2 + 1];

    float l = 0.f;
    float acc[16] = {};

    for (int rnd = 0; rnd < 2; ++rnd) {
        if (rnd) __syncthreads();              // drain prev round's readers
        {   // stage 64-key K/V tile
            int key = tid >> 2, part = tid & 3;
            size_t g = hdbase + (size_t)(ks * 128 + rnd * 64 + key) * D_ + part * 4;
            *(float4*)&kl[key][part * 4] = *(const float4*)&K[g];
            *(float4*)&vl[key][part * 4] = *(const float4*)&V[g];
        }
        __syncthreads();

        const int ml0 = wave * 16;
#pragma unroll 4
        for (int i = 0; i < 16; ++i) {
            const int ml = ml0 + i;
            const int mc = rnd * 64 + ml;
            // bucket path first: independent of K loads, overlaps the dot
            float dx = cx - ckrd[mc][0], dy = cy - ckrd[mc][1];
            float dist = sqrtf(fmaf(dx, dx, dy * dy));
            int bucket = (int)(dist * 32.0f);
            bucket = bucket > (NB - 1) ? (NB - 1) : bucket;
            float qe = qel[lane][bucket];
            const float4* kp = (const float4*)&kl[ml][0];
            const float4 k0 = kp[0], k1 = kp[1], k2 = kp[2], k3 = kp[3];
            // tree-structured dot: 4 independent 4-FMA chains
            float d0 = fmaf(q0.x,k0.x, fmaf(q0.y,k0.y, fmaf(q0.z,k0.z, q0.w*k0.w)));
            float d1 = fmaf(q1.x,k1.x, fmaf(q1.y,k1.y, fmaf(q1.z,k1.z, q1.w*k1.w)));
            float d2 = fmaf(q2.x,k2.x, fmaf(q2.y,k2.y, fmaf(q2.z,k2.z, q2.w*k2.w)));
            float d3 = fmaf(q3.x,k3.x, fmaf(q3.y,k3.y, fmaf(q3.z,k3.z, q3.w*k3.w)));
            float p = __expf(fmaf((d0 + d1) + (d2 + d3), 0.25f, qe));
            l += p;
            const float4* vp = (const float4*)&vl[ml][0];
            const float4 v0 = vp[0], v1 = vp[1], v2 = vp[2], v3 = vp[3];
            acc[0]  += p * v0.x; acc[1]  += p * v0.y; acc[2]  += p * v0.z; acc[3]  += p * v0.w;
            acc[4]  += p * v1.x; acc[5]  += p * v1.y; acc[6]  += p * v1.z; acc[7]  += p * v1.w;
            acc[8]  += p * v2.x; acc[9]  += p * v2.y; acc[10] += p * v2.z; acc[11] += p * v2.w;
            acc[12] += p * v3.x; acc[13] += p * v3.y; acc[14] += p * v3.z; acc[15] += p * v3.w;
        }
    }

    __syncthreads();
    accl[wave][lane][16] = l;
#pragma unroll
    for (int j = 0; j < 16; ++j) accl[wave][lane][j] = acc[j];
    __syncthreads();

    float* pb = P + (size_t)bid * (64 * 17);
    for (int i = tid; i < 64 * 17; i += 256) {
        int r = i / 17, j = i - r * 17;
        pb[i] = accl[0][r][j] + accl[1][r][j] + accl[2][r][j] + accl[3][r][j];
    }
}

// ---------------- O-proj: combine KS=4 partials + GEMV + residual (512 blocks) -------
__global__ __launch_bounds__(256) void oproj_kernel(
    const float* __restrict__ P, const float* __restrict__ WO,
    const float* __restrict__ hres, float* __restrict__ X1)
{
    const int tid = threadIdx.x;
    const int gr0 = blockIdx.x * 4;
    __shared__ float AOls[4][128];
    __shared__ float lsl[4][8];

    if (tid < 32) {
        int r = tid >> 3, hh = tid & 7;
        int gr = gr0 + r;
        int b = gr >> 9, n = gr & (N_ - 1);
        int chunk = n >> 6, rl = n & 63;
        size_t base = ((size_t)(((b * H_ + hh) * 8 + chunk) * KS)) * (64 * 17) + (size_t)rl * 17;
        float l = 0.f;
#pragma unroll
        for (int s = 0; s < KS; ++s) l += P[base + (size_t)s * (64 * 17) + 16];
        lsl[r][hh] = l;
    }
    float asum[2];
#pragma unroll
    for (int j = 0; j < 2; ++j) {
        int i = tid + j * 256;
        int r = i >> 7, d = i & 127;
        int gr = gr0 + r;
        int b = gr >> 9, n = gr & (N_ - 1);
        int chunk = n >> 6, rl = n & 63;
        int hh = d >> 4, dk = d & 15;
        size_t base = ((size_t)(((b * H_ + hh) * 8 + chunk) * KS)) * (64 * 17) + (size_t)rl * 17 + dk;
        float s = 0.f;
#pragma unroll
        for (int ss = 0; ss < KS; ++ss) s += P[base + (size_t)ss * (64 * 17)];
        asum[j] = s;
    }
    __syncthreads();
#pragma unroll
    for (int j = 0; j < 2; ++j) {
        int i = tid + j * 256;
        int r = i >> 7, d = i & 127;
        AOls[r][d] = asum[j] / lsl[r][d >> 4];
    }
    __syncthreads();

    const int wave = tid >> 6;
    const int lane = tid & 63;
    const int col = lane * 2;
    float acc0 = 0.f, acc1 = 0.f;
#pragma unroll 2
    for (int k0 = 0; k0 < D_; k0 += 4) {
        float4 av = *(const float4*)&AOls[wave][k0];
#pragma unroll
        for (int kk = 0; kk < 4; ++kk) {
            float2 bv = *(const float2*)&WO[(size_t)(k0 + kk) * D_ + col];
            float x = (&av.x)[kk];
            acc0 += x * bv.x; acc1 += x * bv.y;
        }
    }
    const int gr = gr0 + wave;
    float2 rv = *(const float2*)&hres[(size_t)gr * D_ + col];
    *(float2*)&X1[(size_t)gr * D_ + col] = make_float2(acc0 + rv.x, acc1 + rv.y);
}

// ---------------- instance-norm stats (128 blocks) ----------------
__global__ __launch_bounds__(256) void stats_kernel(const float* __restrict__ X,
    const float* __restrict__ gamma, const float* __restrict__ beta,
    float* __restrict__ T1, float* __restrict__ T2)
{
    const int b  = blockIdx.x >> 5;
    const int dg = blockIdx.x & 31;
    const int dl = threadIdx.x & 3;
    const int nc = threadIdx.x >> 2;
    const float* xp = X + ((size_t)b * N_ + nc * 8) * D_ + dg * 4 + dl;
    float s = 0.f, q = 0.f;
#pragma unroll
    for (int i = 0; i < 8; ++i) { float x = xp[(size_t)i * D_]; s += x; q += x * x; }
    __shared__ float rs[64][4], rq[64][4];
    rs[nc][dl] = s; rq[nc][dl] = q;
    __syncthreads();
    for (int off = 32; off >= 1; off >>= 1) {
        if (nc < off) { rs[nc][dl] += rs[nc + off][dl]; rq[nc][dl] += rq[nc + off][dl]; }
        __syncthreads();
    }
    if (threadIdx.x < 4) {
        int d = dg * 4 + threadIdx.x;
        float mean = rs[0][threadIdx.x] * (1.0f / N_);
        float var  = rq[0][threadIdx.x] * (1.0f / N_) - mean * mean;
        float r = 1.0f / sqrtf(var + 1e-5f);
        float t1 = r * gamma[d];
        T1[b * D_ + d] = t1;
        T2[b * D_ + d] = beta[d] - mean * t1;
    }
}

// ---------------- FFN1: norm prologue; wave = 4 rows x 128-col slice (512 blocks) ----
__global__ __launch_bounds__(256) void ffn1_kernel(
    const float* __restrict__ X1, const float* __restrict__ T1, const float* __restrict__ T2,
    const float* __restrict__ w1, const float* __restrict__ b1, float* __restrict__ F1)
{
    __shared__ float Als[16][128];
    const int gr0 = blockIdx.x * 16;
    const int b = gr0 >> 9;
#pragma unroll
    for (int i = threadIdx.x * 4; i < 16 * 128; i += 1024) {
        int r = i >> 7, c = i & 127;
        float4 x  = *(const float4*)&X1[(size_t)(gr0 + r) * D_ + c];
        float4 t1 = *(const float4*)&T1[b * D_ + c];
        float4 t2 = *(const float4*)&T2[b * D_ + c];
        float4 y;
        y.x = x.x * t1.x + t2.x; y.y = x.y * t1.y + t2.y;
        y.z = x.z * t1.z + t2.z; y.w = x.w * t1.w + t2.w;
        *(float4*)&Als[r][c] = y;
    }
    __syncthreads();

    const int wave = threadIdx.x >> 6;
    const int lane = threadIdx.x & 63;
    const int rl = wave * 4;
    const int col = blockIdx.y * 128 + lane * 2;

    float acc[4][2] = {};
#pragma unroll 2
    for (int k0 = 0; k0 < D_; k0 += 4) {
        float4 a4[4];
#pragma unroll
        for (int j = 0; j < 4; ++j) a4[j] = *(const float4*)&Als[rl + j][k0];
#pragma unroll
        for (int kk = 0; kk < 4; ++kk) {
            float2 bv = *(const float2*)&w1[(size_t)(k0 + kk) * DFF + col];
#pragma unroll
            for (int j = 0; j < 4; ++j) {
                float x = (&a4[j].x)[kk];
                acc[j][0] += x * bv.x; acc[j][1] += x * bv.y;
            }
        }
    }
    float2 bb = *(const float2*)&b1[col];
#pragma unroll
    for (int j = 0; j < 4; ++j) {
        float o0 = fmaxf(acc[j][0] + bb.x, 0.f);
        float o1 = fmaxf(acc[j][1] + bb.y, 0.f);
        *(float2*)&F1[(size_t)(gr0 + rl + j) * DFF + col] = make_float2(o0, o1);
    }
}

// ---------------- FFN2 split-K (FS=4): 512 blocks, 4 rows/wave, K-slice=128 ----------
__global__ __launch_bounds__(256) void ffn2s_kernel(
    const float* __restrict__ F1, const float* __restrict__ w2, float* __restrict__ Pf)
{
    const int wave = threadIdx.x >> 6;
    const int lane = threadIdx.x & 63;
    const int rbase = __builtin_amdgcn_readfirstlane((blockIdx.x * 4 + wave) * 4);
    const int col = lane * 2;
    const int s = blockIdx.z;
    const int kbeg = s * (DFF / FS);

    float acc[4][2] = {};
#pragma unroll 2
    for (int k0 = kbeg; k0 < kbeg + DFF / FS; k0 += 4) {
        float4 a4[4];
#pragma unroll
        for (int j = 0; j < 4; ++j)
            a4[j] = *(const float4*)&F1[(size_t)(rbase + j) * DFF + k0];
#pragma unroll
        for (int kk = 0; kk < 4; ++kk) {
            float2 bv = *(const float2*)&w2[(size_t)(k0 + kk) * D_ + col];
#pragma unroll
            for (int j = 0; j < 4; ++j) {
                float x = (&a4[j].x)[kk];
                acc[j][0] += x * bv.x; acc[j][1] += x * bv.y;
            }
        }
    }
#pragma unroll
    for (int j = 0; j < 4; ++j)
        *(float2*)&Pf[((size_t)s * (B_ * N_) + rbase + j) * D_ + col] =
            make_float2(acc[j][0], acc[j][1]);
}

// ---------------- FFN2 combine: X2 = sum_s Pf[s] + b2 + (X1*T1+T2) residual ----------
__global__ __launch_bounds__(256) void fcomb_kernel(
    const float* __restrict__ Pf, const float* __restrict__ b2,
    const float* __restrict__ X1, const float* __restrict__ T1, const float* __restrict__ T2,
    float* __restrict__ X2)
{
    int idx = (blockIdx.x * 256 + threadIdx.x) * 4;
    int d = idx & (D_ - 1);
    int b = idx >> 16;
    float4 o  = *(const float4*)&b2[d];
    float4 x1 = *(const float4*)&X1[idx];
    float4 t1 = *(const float4*)&T1[b * D_ + d];
    float4 t2 = *(const float4*)&T2[b * D_ + d];
    o.x += x1.x * t1.x + t2.x; o.y += x1.y * t1.y + t2.y;
    o.z += x1.z * t1.z + t2.z; o.w += x1.w * t1.w + t2.w;
#pragma unroll
    for (int s = 0; s < FS; ++s) {
        float4 p = *(const float4*)&Pf[(size_t)s * (B_ * N_ * D_) + idx];
        o.x += p.x; o.y += p.y; o.z += p.z; o.w += p.w;
    }
    *(float4*)&X2[idx] = o;
}

// ---------------- fused instance-norm stats + apply -> out (128 blocks) --------------
__global__ __launch_bounds__(256) void stats_apply_kernel(const float* __restrict__ X,
    const float* __restrict__ gamma, const float* __restrict__ beta,
    float* __restrict__ Y)
{
    const int b  = blockIdx.x >> 5;
    const int dg = blockIdx.x & 31;
    const int dl = threadIdx.x & 3;
    const int nc = threadIdx.x >> 2;
    const float* xp = X + ((size_t)b * N_ + nc * 8) * D_ + dg * 4 + dl;
    float s = 0.f, q = 0.f;
#pragma unroll
    for (int i = 0; i < 8; ++i) { float x = xp[(size_t)i * D_]; s += x; q += x * x; }
    __shared__ float rs[64][4], rq[64][4];
    __shared__ float t1l[4], t2l[4];
    rs[nc][dl] = s; rq[nc][dl] = q;
    __syncthreads();
    for (int off = 32; off >= 1; off >>= 1) {
        if (nc < off) { rs[nc][dl] += rs[nc + off][dl]; rq[nc][dl] += rq[nc + off][dl]; }
        __syncthreads();
    }
    if (threadIdx.x < 4) {
        int d = dg * 4 + threadIdx.x;
        float mean = rs[0][threadIdx.x] * (1.0f / N_);
        float var  = rq[0][threadIdx.x] * (1.0f / N_) - mean * mean;
        float r = 1.0f / sqrtf(var + 1e-5f);
        float t1 = r * gamma[d];
        t1l[threadIdx.x] = t1;
        t2l[threadIdx.x] = beta[d] - mean * t1;
    }
    __syncthreads();
    const float t1 = t1l[dl], t2 = t2l[dl];
    float* yp = Y + ((size_t)b * N_ + nc * 8) * D_ + dg * 4 + dl;
#pragma unroll
    for (int i = 0; i < 8; ++i) yp[(size_t)i * D_] = xp[(size_t)i * D_] * t1 + t2;
}

extern "C" void kernel_launch(void* const* d_in, const int* in_sizes, int n_in,
                              void* d_out, int out_size, void* d_ws, size_t ws_size,
                              hipStream_t stream)
{
    const float* h      = (const float*)d_in[0];
    const float* coords = (const float*)d_in[1];
    const float* W_Q    = (const float*)d_in[2];
    const float* W_K    = (const float*)d_in[3];
    const float* W_V    = (const float*)d_in[4];
    const float* W_O    = (const float*)d_in[5];
    const float* emb    = (const float*)d_in[6];
    const float* w1     = (const float*)d_in[7];
    const float* b1     = (const float*)d_in[8];
    const float* w2     = (const float*)d_in[9];
    const float* b2     = (const float*)d_in[10];
    const float* g1     = (const float*)d_in[11];
    const float* be1    = (const float*)d_in[12];
    const float* g2     = (const float*)d_in[13];
    const float* be2    = (const float*)d_in[14];
    float* out = (float*)d_out;

    float* ws = (float*)d_ws;
    const size_t R = (size_t)B_ * N_;          // 2048 rows
    float* Qb  = ws;
    float* Kb  = Qb + R * D_;
    float* Vb  = Kb + R * D_;
    float* QEb = Vb + R * D_;                  // R*H*NB
    float* X1  = QEb + R * H_ * NB;
    float* F1  = X1 + R * D_;                  // R * DFF
    float* X2  = F1 + R * DFF;
    float* Pb  = X2 + R * D_;                  // 1024 * 64 * 17
    float* Pf  = Pb + (size_t)1024 * 64 * 17;  // FS * R * D
    float* T1a = Pf + (size_t)FS * R * D_;
    float* T2a = T1a + B_ * D_;

    // 1. Q,K,V projections + QE table (768 blocks)
    qkv_qe_kernel<<<dim3(256, 1, 3), 256, 0, stream>>>(
        h, W_Q, W_K, W_V, emb, Qb, Kb, Vb, QEb);
    // 2. attention (KS=4, 1024 blocks, 2-round staging) -> partials
    attn7_kernel<<<dim3(1024), 256, 0, stream>>>(Qb, Kb, Vb, QEb, coords, Pb);
    // 3. O-projection (combine prologue + residual h; 512 blocks)
    oproj_kernel<<<dim3((int)R / 4), 256, 0, stream>>>(Pb, W_O, h, X1);
    // 4. instance-norm-1 stats (128 blocks)
    stats_kernel<<<dim3(B_ * 32), 256, 0, stream>>>(X1, g1, be1, T1a, T2a);
    // 5. FFN1 (norm prologue; relu; 512 blocks)
    ffn1_kernel<<<dim3(128, 4), 256, 0, stream>>>(X1, T1a, T2a, w1, b1, F1);
    // 6. FFN2 split-K partials (FS=4; 512 blocks)
    ffn2s_kernel<<<dim3(128, 1, FS), 256, 0, stream>>>(F1, w2, Pf);
    // 7. FFN2 combine (+bias, + inline norm1(X1) residual; 256 blocks)
    fcomb_kernel<<<dim3((int)(R * D_) / 1024), 256, 0, stream>>>(Pf, b2, X1, T1a, T2a, X2);
    // 8. instance-norm-2 stats + apply -> out (128 blocks)
    stats_apply_kernel<<<dim3(B_ * 32), 256, 0, stream>>>(X2, g2, be2, out);
}